// Round 7
// baseline (480.247 us; speedup 1.0000x reference)
//
#include <hip/hip_runtime.h>

// CorrNeigh: out[b, i*7+j, h, w] = sum_c x[b,c,h,w] * y[b,c,h+i-3,w+j-3]
// B=8 C=128 H=W=256, K=7, PAD=3, fp32.
//
// Round 7: single-wave workgroups. R3/R5/R6 showed occupancy stuck at
// 20-40% with 448-thread (7-wave) blocks despite VGPR headroom -> block
// packing granularity suspected. Now: block = 1 wave (64 thr), grid 7168;
// each wave owns one (64w x 8h tile, dy). Occupancy is then purely
// VGPR-bound (cap 128 -> 4 waves/SIMD -> 50%).
//  - 8 px/lane (56 FMA per 64B L1 traffic, 2x the FMA/byte of the 4-px R6).
//  - Halo: 6 __shfl from lane+-1 + cndmask override at tile edges
//    (R3-proven); pad rows/edges via zbuf pointer redirect, stride 0
//    (R5/R6-proven) -> no masks/mults in the hot loop.
//  - 2-deep pinned pipeline (asm memory clobber after each issue group,
//    R6-proven to survive regalloc).
//  - Swizzle: XCD = batch image; within XCD dy varies fastest -> 7
//    consecutive blocks share the same x tile (L1/L2 reuse across dy).

#define Bq 8
#define Cq 128
#define Hq 256
#define Wq 256
#define Kq 7
#define TILE_H 8
#define TILE_W 64
#define CS (Hq * Wq)

__global__ __launch_bounds__(64, 4)
void corr7_kernel(const float* __restrict__ x, const float* __restrict__ y,
                  float* __restrict__ out, const float* __restrict__ zbuf)
{
    const int lane = threadIdx.x;   // 0..63
    const int lw   = lane & 7;      // w-octet
    const int lr   = lane >> 3;     // row within tile (0..7)

    // swizzle: XCD k (= raw&7) gets batch image k; within an XCD successive
    // blocks walk dy fastest, then tiles (tw fastest, then th).
    const int raw = (int)blockIdx.x;      // 0..7167
    const int b   = raw & 7;              // batch == XCD
    const int q   = raw >> 3;             // 0..895
    const int tile = q / Kq;              // 0..127
    const int dy   = q - tile * Kq;       // 0..6
    const int tw = tile & 3;              // 4 w-tiles
    const int th = tile >> 2;             // 32 h-tiles

    const int h0 = th * TILE_H;
    const int w0 = tw * TILE_W;
    const int wq = w0 + 8 * lw;           // lane's first output column

    const size_t base = (size_t)b * Cq * CS;

    // validity -> zbuf redirect (stride 0), pad reads return 0
    const int gy  = h0 + lr + dy - 3;
    const bool vo = ((unsigned)gy < (unsigned)Hq);
    const bool isL = (lw == 0);
    const bool isR = (lw == 7);
    const bool vl = vo && isL && (tw != 0);
    const bool vr = vo && isR && (tw != 3);

    const float* yrow = y + base + (size_t)(vo ? gy : 0) * Wq;

    const float* px = x + base + (size_t)(h0 + lr) * Wq + wq;
    const float* po = vo ? (yrow + wq) : zbuf;
    // halo quad: lw==0 -> cols wq-4..wq-1 ; lw==7 -> cols wq+8..wq+11
    const float* ph = vl ? (yrow + wq - 4) : (vr ? (yrow + wq + 8) : zbuf);

    const unsigned so = vo ? (unsigned)CS : 0u;
    const unsigned sh = (vl || vr) ? (unsigned)CS : 0u;

    const int lm1 = (lane + 63) & 63;
    const int lp1 = (lane + 1) & 63;

    float acc[Kq][8];
#pragma unroll
    for (int j = 0; j < Kq; ++j)
#pragma unroll
        for (int r = 0; r < 8; ++r) acc[j][r] = 0.f;

    // 2-deep pipeline register sets: x octet (2 quads), y octet (2), halo (1)
    float4 fxa[2], fxb[2], fy0[2], fy1[2], fh[2];

#define ISSUE(S)                                   \
    fxa[S] = *(const float4*)px;                   \
    fxb[S] = *(const float4*)(px + 4);             \
    fy0[S] = *(const float4*)po;                   \
    fy1[S] = *(const float4*)(po + 4);             \
    fh[S]  = *(const float4*)ph;                   \
    px += CS; po += so; ph += sh;                  \
    asm volatile("" ::: "memory");

#define FMABLK(S) {                                                       \
    float l0 = __shfl(fy1[S].y, lm1);  /* neighbor elems 5,6,7 */         \
    float l1 = __shfl(fy1[S].z, lm1);                                     \
    float l2 = __shfl(fy1[S].w, lm1);                                     \
    float r0 = __shfl(fy0[S].x, lp1);  /* neighbor elems 0,1,2 */         \
    float r1 = __shfl(fy0[S].y, lp1);                                     \
    float r2 = __shfl(fy0[S].z, lp1);                                     \
    l0 = isL ? fh[S].y : l0;  l1 = isL ? fh[S].z : l1;                    \
    l2 = isL ? fh[S].w : l2;                                              \
    r0 = isR ? fh[S].x : r0;  r1 = isR ? fh[S].y : r1;                    \
    r2 = isR ? fh[S].z : r2;                                              \
    const float yw[14] = { l0, l1, l2,                                    \
                           fy0[S].x, fy0[S].y, fy0[S].z, fy0[S].w,        \
                           fy1[S].x, fy1[S].y, fy1[S].z, fy1[S].w,        \
                           r0, r1, r2 };                                  \
    const float xv[8]  = { fxa[S].x, fxa[S].y, fxa[S].z, fxa[S].w,        \
                           fxb[S].x, fxb[S].y, fxb[S].z, fxb[S].w };      \
    _Pragma("unroll")                                                     \
    for (int j = 0; j < Kq; ++j)                                          \
        _Pragma("unroll")                                                 \
        for (int r = 0; r < 8; ++r)                                       \
            acc[j][r] = fmaf(xv[r], yw[r + j], acc[j][r]);                \
}

    ISSUE(0)   // ch 0
    ISSUE(1)   // ch 1

#pragma unroll 1
    for (int c = 0; c < Cq - 2; c += 2) {
        FMABLK(0)
        ISSUE(0)      // ch c+2
        FMABLK(1)
        ISSUE(1)      // ch c+3
    }
    FMABLK(0)   // ch 126
    FMABLK(1)   // ch 127

#undef ISSUE
#undef FMABLK

    // epilogue: this wave writes k-planes dy*7 .. dy*7+6 (one octet each)
    size_t obase = (((size_t)b * (Kq * Kq) + (size_t)dy * Kq) * Hq
                    + (h0 + lr)) * Wq + wq;
#pragma unroll
    for (int j = 0; j < Kq; ++j) {
        float4 o0 = {acc[j][0], acc[j][1], acc[j][2], acc[j][3]};
        float4 o1 = {acc[j][4], acc[j][5], acc[j][6], acc[j][7]};
        *(float4*)(out + obase)     = o0;
        *(float4*)(out + obase + 4) = o1;
        obase += (size_t)CS;  // next k-plane
    }
}

extern "C" void kernel_launch(void* const* d_in, const int* in_sizes, int n_in,
                              void* d_out, int out_size, void* d_ws, size_t ws_size,
                              hipStream_t stream) {
    const float* x = (const float*)d_in[0];
    const float* y = (const float*)d_in[1];
    float* out = (float*)d_out;

    // zero pad-source region (invalid-lane pointers aim here, stride 0)
    hipMemsetAsync(d_ws, 0, 256, stream);

    dim3 grid(Bq * 32 * 4 * Kq);   // 7168 waves: 8 b x (32h x 4w tiles) x 7 dy
    dim3 block(64);
    hipLaunchKernelGGL(corr7_kernel, grid, block, 0, stream,
                       x, y, out, (const float*)d_ws);
}

// Round 8
// 313.177 us; speedup vs baseline: 1.5335x; 1.5335x over previous
//
#include <hip/hip_runtime.h>

// CorrNeigh: out[b, i*7+j, h, w] = sum_c x[b,c,h,w] * y[b,c,h+i-3,w+j-3]
// B=8 C=128 H=W=256, K=7, PAD=3, fp32.
//
// Round 8: global_load_lds + counted-vmcnt ring pipeline (T3/T4).
// R4-R7 showed register-resident pipelines always lose: the allocator
// targets 64 VGPR and either spills (R4/R7: 150-6000MB scratch) or
// serializes the loads (R5/R6: VALUBusy <=24%). Direct-to-LDS DMA costs
// ZERO VGPRs for in-flight data -> depth-4 prefetch with a small regfile.
//
//  - Block 448 (7 waves = dy), tile 64w x 8h, 8 px/lane, acc[7][8].
//  - Slot = 7168B = 448 threads x 16B: y halo 14 rows x 80 f32 (5120B..
//    actually 4480B) + x 8x64 (2048B) + 640B slack. ONE DMA instr per wave
//    per channel. Per-lane global src (halo/pad via zbuf redirect, stride 0);
//    LDS dest linear (m104/m173 semantics).
//  - 5-slot ring, prefetch 4: loop top = s_waitcnt vmcnt(3) lgkmcnt(0) +
//    s_barrier; then issue ch c+4 into slot (c+4)%5 = the slot read at c-1
//    (all its reads completed before this barrier -> race-free); then
//    6x ds_read_b128 + 56 FMA. vmcnt never drains in steady state.
//  - waves_per_eu(4,5): stops the compiler's 8-wave/64-VGPR spill chase.
//  - XCD-chunked swizzle: one batch image per XCD (halo rows L2-resident).

#define Bq 8
#define Cq 128
#define Hq 256
#define Wq 256
#define Kq 7
#define TILE_H 8
#define TILE_W 64
#define NTHR 448
#define CS (Hq * Wq)
#define SLOT 7168
#define NSLOT 5
#define YB 4480          // bytes of y-halo region in a slot (14*80*4)

typedef const __attribute__((address_space(1))) void* gptr_t;
typedef __attribute__((address_space(3))) void* lptr_t;

__device__ __forceinline__ void dma16(const float* g, char* l) {
    __builtin_amdgcn_global_load_lds((gptr_t)g, (lptr_t)l, 16, 0, 0);
}

__global__ __launch_bounds__(NTHR)
__attribute__((amdgpu_waves_per_eu(4, 5)))
void corr7_kernel(const float* __restrict__ x, const float* __restrict__ y,
                  float* __restrict__ out, const float* __restrict__ zbuf)
{
    __shared__ __align__(16) char smem[NSLOT * SLOT];

    const int t    = threadIdx.x;
    const int wave = t >> 6;        // dy index (0..6)
    const int lane = t & 63;
    const int lw   = lane & 7;      // w-octet
    const int lr   = lane >> 3;     // row in tile (0..7)

    // XCD-chunked swizzle: XCD k gets tiles [k*128,(k+1)*128) = one image
    int bid = (int)blockIdx.x;
    bid = (bid & 7) * 128 + (bid >> 3);
    const int tw = bid & 3;
    const int th = (bid >> 2) & 31;
    const int b  = bid >> 7;

    const int h0 = th * TILE_H;
    const int w0 = tw * TILE_W;
    const int wq = w0 + 8 * lw;

    const size_t base = (size_t)b * Cq * CS;

    // ---- staging role: thread t loads 16B chunk #t of each slot ----
    const float* src;
    unsigned sstep;
    {
        const int k = t;
        if (k < 280) {                       // y halo: 14 rows x 80 floats
            const int f = 4 * k;
            const int r = f / 80, q = f - 80 * r;
            const int gy = h0 + r - 3;
            const int gx = w0 - 8 + q;       // 16B chunk uniformly valid
            const bool v = ((unsigned)gy < (unsigned)Hq) &&
                           ((unsigned)gx < (unsigned)Wq);
            src   = v ? (y + base + (size_t)gy * Wq + gx) : zbuf;
            sstep = v ? (unsigned)CS : 0u;
        } else if (k < 408) {                // x tile: 8 rows x 64 floats
            const int f = 4 * (k - 280);
            const int r = f >> 6, q = f & 63;
            src   = x + base + (size_t)(h0 + r) * Wq + (w0 + q);
            sstep = (unsigned)CS;
        } else {                             // filler
            src   = zbuf;
            sstep = 0u;
        }
    }

    // ---- compute-role LDS byte offsets (within a slot) ----
    const int ybase = (lr + wave) * 320 + lw * 32 + 16; // row R=lr+wave, quad@8lw+4
    const int xbase = YB + lr * 256 + lw * 32;

    float acc[Kq][8];
#pragma unroll
    for (int j = 0; j < Kq; ++j)
#pragma unroll
        for (int r = 0; r < 8; ++r) acc[j][r] = 0.f;

    unsigned soff_r = 0;
    unsigned soff_w = 4u * SLOT;

    // prologue: fill slots 0..3 (channels 0..3)
    dma16(src, smem + 0 * SLOT + t * 16); src += sstep;
    dma16(src, smem + 1 * SLOT + t * 16); src += sstep;
    dma16(src, smem + 2 * SLOT + t * 16); src += sstep;
    dma16(src, smem + 3 * SLOT + t * 16); src += sstep;

#define BODY(WAITSTR, DO_ISSUE)                                           \
    {                                                                     \
        asm volatile(WAITSTR ::: "memory");                               \
        __builtin_amdgcn_s_barrier();                                     \
        if (DO_ISSUE) { dma16(src, smem + soff_w + t * 16); src += sstep; } \
        const char* sr = smem + soff_r;                                   \
        const float4 q0 = *(const float4*)(sr + ybase);                   \
        const float4 q1 = *(const float4*)(sr + ybase + 16);              \
        const float4 q2 = *(const float4*)(sr + ybase + 32);              \
        const float4 q3 = *(const float4*)(sr + ybase + 48);              \
        const float4 xq0 = *(const float4*)(sr + xbase);                  \
        const float4 xq1 = *(const float4*)(sr + xbase + 16);             \
        float yf[16];                                                     \
        *(float4*)(yf)      = q0;  *(float4*)(yf + 4)  = q1;              \
        *(float4*)(yf + 8)  = q2;  *(float4*)(yf + 12) = q3;              \
        float xv[8];                                                      \
        *(float4*)(xv)      = xq0; *(float4*)(xv + 4)  = xq1;             \
        _Pragma("unroll")                                                 \
        for (int j = 0; j < Kq; ++j)                                      \
            _Pragma("unroll")                                             \
            for (int r = 0; r < 8; ++r)                                   \
                acc[j][r] = fmaf(xv[r], yf[1 + j + r], acc[j][r]);        \
        soff_w = soff_r;                                                  \
        soff_r += SLOT; if (soff_r == NSLOT * SLOT) soff_r = 0;           \
    }

    // steady state: channels 0..123, always 4 in flight
#pragma unroll 1
    for (int c = 0; c < Cq - 4; ++c) {
        BODY("s_waitcnt vmcnt(3) lgkmcnt(0)", true)
    }
    // drain: channels 124..127
    BODY("s_waitcnt vmcnt(3) lgkmcnt(0)", false)
    BODY("s_waitcnt vmcnt(2) lgkmcnt(0)", false)
    BODY("s_waitcnt vmcnt(1) lgkmcnt(0)", false)
    BODY("s_waitcnt vmcnt(0) lgkmcnt(0)", false)
#undef BODY

    // epilogue: wave writes k-planes wave*7 .. wave*7+6 (one octet each)
    size_t obase = (((size_t)b * (Kq * Kq) + (size_t)wave * Kq) * Hq
                    + (h0 + lr)) * Wq + wq;
#pragma unroll
    for (int j = 0; j < Kq; ++j) {
        float4 o0 = {acc[j][0], acc[j][1], acc[j][2], acc[j][3]};
        float4 o1 = {acc[j][4], acc[j][5], acc[j][6], acc[j][7]};
        *(float4*)(out + obase)     = o0;
        *(float4*)(out + obase + 4) = o1;
        obase += (size_t)CS;
    }
}

extern "C" void kernel_launch(void* const* d_in, const int* in_sizes, int n_in,
                              void* d_out, int out_size, void* d_ws, size_t ws_size,
                              hipStream_t stream) {
    const float* x = (const float*)d_in[0];
    const float* y = (const float*)d_in[1];
    float* out = (float*)d_out;

    // zero pad-source region (invalid-lane pointers aim here, stride 0)
    hipMemsetAsync(d_ws, 0, 256, stream);

    dim3 grid(Bq * 32 * 4);   // 1024 tiles: 8 b x 32 h x 4 w
    dim3 block(NTHR);
    hipLaunchKernelGGL(corr7_kernel, grid, block, 0, stream,
                       x, y, out, (const float*)d_ws);
}

// Round 9
// 309.377 us; speedup vs baseline: 1.5523x; 1.0123x over previous
//
#include <hip/hip_runtime.h>

// CorrNeigh: out[b, i*7+j, h, w] = sum_c x[b,c,h,w] * y[b,c,h+i-3,w+j-3]
// B=8 C=128 H=W=256, K=7, PAD=3, fp32.
//
// Round 9: R8 (DMA ring, 313us) + three counter-driven fixes:
//  1. Bank-conflict-free LDS pitches: y rows 84 floats (21 chunks), x rows
//     68 floats (17 chunks). Start-word spread = all 32 banks, 8 words each
//     (the b128 minimum). R8's pitch-80/64 used only 16 banks (5.1e7
//     conflict cycles ~= 84us).
//  2. amdgpu_waves_per_eu(4) (min-only form): VGPR budget 128, stops the
//     8-wave/64-VGPR allocator target that spilled ~120MB in R8.
//  3. 2 channels per barrier: ring of 6 slots, steady-state wait
//     vmcnt(2)+lgkmcnt(0), 64 barriers instead of 128.
// Slot layout (7168B = 448 thread-chunks, 1 DMA instr/wave/channel):
//   y: 14 rows x 21 chunks (chunk 20 = pad), bytes [0,4704)
//   x:  8 rows x 17 chunks (chunk 16 = pad), bytes [4704,6880)
//   filler: 18 chunks. Pad/oob chunks -> zbuf (stride 0) = zeros.
// Ring safety: slot written at iter k was read at iter k-1; its ds_reads
// are drained by lgkmcnt(0) before the barrier that precedes the DMA issue.
// Cross-wave visibility: every wave waits ITS vmcnt before the barrier, so
// after the barrier all waves' chunks have landed.

#define Bq 8
#define Cq 128
#define Hq 256
#define Wq 256
#define Kq 7
#define TILE_H 8
#define TILE_W 64
#define NTHR 448
#define CS (Hq * Wq)
#define SLOT 7168
#define NSLOT 6
#define YPITCH_B 336   // 84 floats
#define XBASE_B  4704  // 294 chunks * 16B
#define XPITCH_B 272   // 68 floats

typedef const __attribute__((address_space(1))) void* gptr_t;
typedef __attribute__((address_space(3))) void* lptr_t;

__device__ __forceinline__ void dma16(const float* g, char* l) {
    __builtin_amdgcn_global_load_lds((gptr_t)g, (lptr_t)l, 16, 0, 0);
}

__global__ __launch_bounds__(NTHR)
__attribute__((amdgpu_waves_per_eu(4)))
void corr7_kernel(const float* __restrict__ x, const float* __restrict__ y,
                  float* __restrict__ out, const float* __restrict__ zbuf)
{
    __shared__ __align__(16) char smem[NSLOT * SLOT];

    const int t    = threadIdx.x;
    const int wave = t >> 6;        // dy index (0..6)
    const int lane = t & 63;
    const int lw   = lane & 7;      // w-octet
    const int lr   = lane >> 3;     // row in tile (0..7)

    // XCD-chunked swizzle: XCD k gets tiles [k*128,(k+1)*128) = one image
    int bid = (int)blockIdx.x;
    bid = (bid & 7) * 128 + (bid >> 3);
    const int tw = bid & 3;
    const int th = (bid >> 2) & 31;
    const int b  = bid >> 7;

    const int h0 = th * TILE_H;
    const int w0 = tw * TILE_W;
    const int wq = w0 + 8 * lw;

    const size_t base = (size_t)b * Cq * CS;

    // ---- staging role: thread t DMAs 16B chunk #t of each slot ----
    const float* src;
    unsigned sstep;
    {
        if (t < 294) {                        // y: 14 rows x 21 chunks
            const int r = t / 21, j = t - 21 * r;
            const int gy = h0 + r - 3;
            const int gx = w0 - 8 + 4 * j;    // chunk covers gx..gx+3
            const bool v = (j < 20) && ((unsigned)gy < (unsigned)Hq) &&
                           (gx >= 0) && (gx + 3 < Wq);
            src   = v ? (y + base + (size_t)gy * Wq + gx) : zbuf;
            sstep = v ? (unsigned)CS : 0u;
        } else if (t < 430) {                 // x: 8 rows x 17 chunks
            const int u = t - 294;
            const int r = u / 17, j = u - 17 * r;
            const bool v = (j < 16);
            src   = v ? (x + base + (size_t)(h0 + r) * Wq + (w0 + 4 * j)) : zbuf;
            sstep = v ? (unsigned)CS : 0u;
        } else {                              // filler
            src   = zbuf;
            sstep = 0u;
        }
    }

    // ---- compute-role LDS byte offsets (within a slot) ----
    // y window: row R=lr+wave, chunks 2lw+1..2lw+4 (words 8lw+4..8lw+19)
    const int yb = (lr + wave) * YPITCH_B + 32 * lw + 16;
    const int xb = XBASE_B + lr * XPITCH_B + 32 * lw;

    float acc[Kq][8];
#pragma unroll
    for (int j = 0; j < Kq; ++j)
#pragma unroll
        for (int r = 0; r < 8; ++r) acc[j][r] = 0.f;

#define COMPUTE(OFF) {                                                    \
    const char* sr = (const char*)smem + (OFF);                           \
    const float4 q0 = *(const float4*)(sr + yb);                          \
    const float4 q1 = *(const float4*)(sr + yb + 16);                     \
    const float4 q2 = *(const float4*)(sr + yb + 32);                     \
    const float4 q3 = *(const float4*)(sr + yb + 48);                     \
    const float4 p0 = *(const float4*)(sr + xb);                          \
    const float4 p1 = *(const float4*)(sr + xb + 16);                     \
    float yf[16];                                                         \
    *(float4*)(yf)      = q0;  *(float4*)(yf + 4)  = q1;                  \
    *(float4*)(yf + 8)  = q2;  *(float4*)(yf + 12) = q3;                  \
    float xv[8];                                                          \
    *(float4*)(xv)      = p0;  *(float4*)(xv + 4)  = p1;                  \
    _Pragma("unroll")                                                     \
    for (int j = 0; j < Kq; ++j)                                          \
        _Pragma("unroll")                                                 \
        for (int r = 0; r < 8; ++r)                                       \
            acc[j][r] = fmaf(xv[r], yf[1 + j + r], acc[j][r]);            \
}

    // prologue: DMA channels 0..3 into slots 0..3
#pragma unroll
    for (int c = 0; c < 4; ++c) {
        dma16(src, smem + c * SLOT + t * 16);
        src += sstep;
    }

    unsigned rd = 0;   // slot byte-offset of even channel of this iteration
#pragma unroll 1
    for (int k = 0; k < 62; ++k) {           // channels 2k, 2k+1
        asm volatile("s_waitcnt vmcnt(2) lgkmcnt(0)" ::: "memory");
        __builtin_amdgcn_s_barrier();
        unsigned wr0 = rd + 4u * SLOT; if (wr0 >= NSLOT * SLOT) wr0 -= NSLOT * SLOT;
        unsigned wr1 = wr0 + SLOT;     if (wr1 >= NSLOT * SLOT) wr1 -= NSLOT * SLOT;
        dma16(src, smem + wr0 + t * 16); src += sstep;   // ch 2k+4
        dma16(src, smem + wr1 + t * 16); src += sstep;   // ch 2k+5
        COMPUTE(rd)
        unsigned rd1 = rd + SLOT; if (rd1 >= NSLOT * SLOT) rd1 -= NSLOT * SLOT;
        COMPUTE(rd1)
        rd += 2u * SLOT; if (rd >= NSLOT * SLOT) rd -= NSLOT * SLOT;
    }
    // drain: channels 124..127 (no more issues)
    {
        asm volatile("s_waitcnt vmcnt(2) lgkmcnt(0)" ::: "memory");
        __builtin_amdgcn_s_barrier();
        COMPUTE(rd)
        unsigned rd1 = rd + SLOT; if (rd1 >= NSLOT * SLOT) rd1 -= NSLOT * SLOT;
        COMPUTE(rd1)
        rd += 2u * SLOT; if (rd >= NSLOT * SLOT) rd -= NSLOT * SLOT;

        asm volatile("s_waitcnt vmcnt(0) lgkmcnt(0)" ::: "memory");
        __builtin_amdgcn_s_barrier();
        COMPUTE(rd)
        rd1 = rd + SLOT; if (rd1 >= NSLOT * SLOT) rd1 -= NSLOT * SLOT;
        COMPUTE(rd1)
    }
#undef COMPUTE

    // epilogue: wave writes k-planes wave*7 .. wave*7+6 (one octet each)
    size_t obase = (((size_t)b * (Kq * Kq) + (size_t)wave * Kq) * Hq
                    + (h0 + lr)) * Wq + wq;
#pragma unroll
    for (int j = 0; j < Kq; ++j) {
        float4 o0 = {acc[j][0], acc[j][1], acc[j][2], acc[j][3]};
        float4 o1 = {acc[j][4], acc[j][5], acc[j][6], acc[j][7]};
        *(float4*)(out + obase)     = o0;
        *(float4*)(out + obase + 4) = o1;
        obase += (size_t)CS;
    }
}

extern "C" void kernel_launch(void* const* d_in, const int* in_sizes, int n_in,
                              void* d_out, int out_size, void* d_ws, size_t ws_size,
                              hipStream_t stream) {
    const float* x = (const float*)d_in[0];
    const float* y = (const float*)d_in[1];
    float* out = (float*)d_out;

    // zero pad-source region (invalid/pad chunks aim here, stride 0)
    hipMemsetAsync(d_ws, 0, 256, stream);

    dim3 grid(Bq * 32 * 4);   // 1024 tiles: 8 b x 32 h x 4 w
    dim3 block(NTHR);
    hipLaunchKernelGGL(corr7_kernel, grid, block, 0, stream,
                       x, y, out, (const float*)d_ws);
}